// Round 1
// baseline (262.250 us; speedup 1.0000x reference)
//
#include <hip/hip_runtime.h>

#define BB 4
#define AA 100000
#define MM 32
#define NC 80

// ws layout: [0] float cls_sum, [1] float reg_sum, [2] uint pos_count, [3] pad,
//            codes (signed char, BB*AA) start at byte offset 16.

__global__ __launch_bounds__(256) void targets_kernel(
    const float* __restrict__ anchors,      // AA*4
    const float* __restrict__ annotations,  // BB*MM*5
    const float* __restrict__ regression,   // BB*AA*4
    float* __restrict__ acc,
    signed char* __restrict__ codes)
{
    __shared__ float ann[MM * 5];
    const int b = blockIdx.y;
    const int tid = threadIdx.x;
    if (tid < MM * 5) ann[tid] = annotations[b * MM * 5 + tid];
    __syncthreads();

    const int a = blockIdx.x * blockDim.x + tid;
    float reg_sum = 0.0f;
    int pos_cnt = 0;

    if (a < AA) {
        const float ax1 = anchors[a * 4 + 0];
        const float ay1 = anchors[a * 4 + 1];
        const float ax2 = anchors[a * 4 + 2];
        const float ay2 = anchors[a * 4 + 3];
        // exact IEEE ops (no FMA contraction) to match numpy bit-for-bit:
        const float area_a = __fmul_rn(__fsub_rn(ax2, ax1), __fsub_rn(ay2, ay1));

        float best_iou = -1.0f;
        int best = 0;
        #pragma unroll
        for (int j = 0; j < MM; ++j) {
            const float bx1 = ann[j * 5 + 0];
            const float by1 = ann[j * 5 + 1];
            const float bx2 = ann[j * 5 + 2];
            const float by2 = ann[j * 5 + 3];
            const float ix1 = fmaxf(ax1, bx1);
            const float iy1 = fmaxf(ay1, by1);
            const float ix2 = fminf(ax2, bx2);
            const float iy2 = fminf(ay2, by2);
            const float iw = fmaxf(__fsub_rn(ix2, ix1), 0.0f);
            const float ih = fmaxf(__fsub_rn(iy2, iy1), 0.0f);
            const float inter = __fmul_rn(iw, ih);
            const float area_b = __fmul_rn(__fsub_rn(bx2, bx1), __fsub_rn(by2, by1));
            const float uni = __fsub_rn(__fadd_rn(area_a, area_b), inter);
            const float iou = __fdiv_rn(inter, fmaxf(uni, 1e-8f));
            if (iou > best_iou) { best_iou = iou; best = j; }  // strict > keeps first max (argmax semantics)
        }

        const bool pos = best_iou >= 0.5f;
        const bool ign = (best_iou > 0.4f) && !pos;
        const float cx = (ax1 + ax2) * 0.5f;
        const float cy = (ay1 + ay2) * 0.5f;
        const bool inside = (cx >= 0.0f) && (cx < 800.0f) && (cy >= 0.0f) && (cy < 800.0f);

        // state: pos->1, ign->-1, neg->0; !inside overrides to -1.
        // code: -2 = state==-1 (excluded from cls loss), -1 = valid negative, 0..79 = positive class.
        signed char code;
        if (!inside || ign) code = -2;
        else if (pos)       code = (signed char)(int)ann[best * 5 + 4];
        else                code = -1;
        codes[(size_t)b * AA + a] = code;

        const bool pos_eff = pos && inside;   // states==1 after inside override
        if (pos_eff) {
            pos_cnt = 1;
            const float aw = ax2 - ax1;
            const float ah = ay2 - ay1;
            const float bx1 = ann[best * 5 + 0];
            const float by1 = ann[best * 5 + 1];
            const float bx2 = ann[best * 5 + 2];
            const float by2 = ann[best * 5 + 3];
            float t[4];
            t[0] = ((bx1 - ax1) / aw) / 0.2f;
            t[1] = ((by1 - ay1) / ah) / 0.2f;
            t[2] = ((bx2 - ax2) / aw) / 0.2f;
            t[3] = ((by2 - ay2) / ah) / 0.2f;
            const float* rg = regression + (((size_t)b * AA + a) * 4);
            #pragma unroll
            for (int k = 0; k < 4; ++k) {
                const float d = fabsf(rg[k] - t[k]);
                const float l1 = (d < (1.0f / 9.0f)) ? (4.5f * d * d) : (d - (0.5f / 9.0f));
                reg_sum += l1;
            }
        }
    }

    // wave (64) reduce, then cross-wave via LDS
    #pragma unroll
    for (int off = 32; off > 0; off >>= 1) {
        reg_sum += __shfl_down(reg_sum, off);
        pos_cnt += __shfl_down(pos_cnt, off);
    }
    __shared__ float wsum[4];
    __shared__ int   wcnt[4];
    const int wave = tid >> 6, lane = tid & 63;
    if (lane == 0) { wsum[wave] = reg_sum; wcnt[wave] = pos_cnt; }
    __syncthreads();
    if (tid == 0) {
        const float s = wsum[0] + wsum[1] + wsum[2] + wsum[3];
        const int   c = wcnt[0] + wcnt[1] + wcnt[2] + wcnt[3];
        atomicAdd(&acc[1], s);
        atomicAdd((unsigned int*)acc + 2, (unsigned int)c);
    }
}

__global__ __launch_bounds__(256) void focal_kernel(
    const float* __restrict__ cls,          // BB*AA*NC, read as float4
    const signed char* __restrict__ codes,  // BB*AA
    float* __restrict__ acc)
{
    const int N4 = BB * AA * (NC / 4);  // 8,000,000 float4s; 80 % 4 == 0 so each float4 is within one anchor
    float sum = 0.0f;
    const int stride = gridDim.x * blockDim.x;
    for (int i = blockIdx.x * blockDim.x + threadIdx.x; i < N4; i += stride) {
        const int anchor = i / 20;              // magic-mul division
        const int cbase = (i - anchor * 20) * 4;
        const int code = codes[anchor];
        if (code == -2) continue;               // state==-1: excluded, skip the load entirely
        const float4 v = ((const float4*)cls)[i];
        const float px[4] = { v.x, v.y, v.z, v.w };
        #pragma unroll
        for (int j = 0; j < 4; ++j) {
            const float p = fminf(fmaxf(px[j], 1e-4f), 0.9999f);
            const float onem = 1.0f - p;
            // common case: label==0 -> 0.75 * p^2 * (-log(1-p))
            float val = 0.75f * p * p * (-__logf(onem));
            if (code == cbase + j) {
                // label==1 -> 0.25 * (1-p)^2 * (-log(p))   (rare: at most 1/80, pos anchors only)
                val = 0.25f * onem * onem * (-__logf(p));
            }
            sum += val;
        }
    }
    #pragma unroll
    for (int off = 32; off > 0; off >>= 1) sum += __shfl_down(sum, off);
    __shared__ float wsum[4];
    const int wave = threadIdx.x >> 6, lane = threadIdx.x & 63;
    if (lane == 0) wsum[wave] = sum;
    __syncthreads();
    if (threadIdx.x == 0) atomicAdd(&acc[0], wsum[0] + wsum[1] + wsum[2] + wsum[3]);
}

__global__ void finalize_kernel(const float* __restrict__ acc, float* __restrict__ out)
{
    const float np = fmaxf((float)(*((const unsigned int*)acc + 2)), 1.0f);
    out[0] = (acc[0] + acc[1]) / np;
}

extern "C" void kernel_launch(void* const* d_in, const int* in_sizes, int n_in,
                              void* d_out, int out_size, void* d_ws, size_t ws_size,
                              hipStream_t stream)
{
    const float* classification = (const float*)d_in[0];  // BB*AA*NC
    const float* regression     = (const float*)d_in[1];  // BB*AA*4
    const float* anchors        = (const float*)d_in[2];  // AA*4
    const float* annotations    = (const float*)d_in[3];  // BB*MM*5
    float* out = (float*)d_out;

    float* acc = (float*)d_ws;
    signed char* codes = (signed char*)d_ws + 16;

    // ws is poisoned to 0xAA before every timed launch — zero the accumulators.
    hipMemsetAsync(d_ws, 0, 16, stream);

    dim3 gA((AA + 255) / 256, BB);
    targets_kernel<<<gA, 256, 0, stream>>>(anchors, annotations, regression, acc, codes);

    focal_kernel<<<4096, 256, 0, stream>>>(classification, codes, acc);

    finalize_kernel<<<1, 1, 0, stream>>>(acc, out);
}